// Round 13
// baseline (234.108 us; speedup 1.0000x reference)
//
#include <hip/hip_runtime.h>
#include <hip/hip_bf16.h>
#include <cstdint>
#include <cstddef>

typedef __bf16 bf16x8 __attribute__((ext_vector_type(8)));
typedef __bf16 bf16x4 __attribute__((ext_vector_type(4)));
typedef float f32x4 __attribute__((ext_vector_type(4)));

#define BATCH 16
#define MDIM 1024
#define NDIM 4096
#define KDIM 1024
#define BM 256
#define BN 256
#define BK 32
#define NT (KDIM / BK)  // 32 K-tiles

__device__ __forceinline__ void gload_lds16(const void* g, void* l) {
  __builtin_amdgcn_global_load_lds(
      (const __attribute__((address_space(1))) void*)g,
      (__attribute__((address_space(3))) void*)l, 16, 0, 0);
}

#define BAR() __builtin_amdgcn_s_barrier()
#define SB() __builtin_amdgcn_sched_barrier(0)
#define FENCE() asm volatile("" ::: "memory")
#define VMC6()                                         \
  do {                                                 \
    asm volatile("s_waitcnt vmcnt(6)" ::: "memory");   \
    SB();                                              \
  } while (0)
#define VMC0()                                         \
  do {                                                 \
    asm volatile("s_waitcnt vmcnt(0)" ::: "memory");   \
    SB();                                              \
  } while (0)

// ---------------------------------------------------------------------------
// Kernel 1: W~[b][o][i] bf16 into workspace (~10us).  (unchanged)
// ---------------------------------------------------------------------------
__global__ __launch_bounds__(256) void modw_kernel(
    const float* __restrict__ weight, const float* __restrict__ y,
    __bf16* __restrict__ wm) {
  const int blk = blockIdx.x;  // 16384
  const int b = blk & 15;
  const int o = blk >> 4;
  const int t = threadIdx.x;
  const float4 w4 = reinterpret_cast<const float4*>(weight + (size_t)o * KDIM)[t];
  const float4 y4 = reinterpret_cast<const float4*>(y + (size_t)b * KDIM)[t];
  const float p0 = w4.x * y4.x, p1 = w4.y * y4.y;
  const float p2 = w4.z * y4.z, p3 = w4.w * y4.w;
  float s = p0 * p0 + p1 * p1 + p2 * p2 + p3 * p3;
#pragma unroll
  for (int off = 32; off >= 1; off >>= 1) s += __shfl_xor(s, off, 64);
  __shared__ float ps[4];
  if ((t & 63) == 0) ps[t >> 6] = s;
  __syncthreads();
  const float tot = ps[0] + ps[1] + ps[2] + ps[3];
  const float scale = 0.03125f;  // 1/sqrt(1024)
  const float dn = scale * rsqrtf(scale * scale * tot + 1e-8f);
  bf16x4 v;
  v[0] = (__bf16)(p0 * dn);
  v[1] = (__bf16)(p1 * dn);
  v[2] = (__bf16)(p2 * dn);
  v[3] = (__bf16)(p3 * dn);
  *reinterpret_cast<bf16x4*>(wm + ((size_t)b * MDIM + o) * KDIM + t * 4) = v;
}

// ---------------------------------------------------------------------------
// Kernel 2: 256x256 tile, BK=32, 8 waves.  BOTH operands staged via
// global_load_lds (the m201/T4 staging regime) -- the fused B reg-staging
// path (32 scalar loads -> 32 VGPR -> cvt -> ds_write + implicit drains),
// which every fused variant R1-R10 carried, is DELETED.  E stays [k][n]
// fp32 in LDS; the transpose dissolves into the fragment read:
// 8 x ds_read_b32 (stride 1KB) + cvt per frag.  A per-8-k-row rotation
// (n' = (n + 8*(k>>3)) & 255), applied via pre-swizzled GLOBAL source
// (16B-aligned, coalescing preserved), makes those reads 2-way bank
// aliased = free (m136).  Tri-buffered (A 3x16KB + B 3x32KB = 144KB):
// stage(t+2) issued at tile t, drained at tile (t+1)'s boundary ->
// vmcnt(6) over queue [stage(t+1) 6 old | stage(t+2) 6 new].  No lgkm
// drain at the sync (no ds_writes exist; frag reads complete pre-barrier
// via the MFMAs' own waits).  cvt-at-read == cvt-at-stage value; identical
// per-acc K-accumulation order -> bit-identical numerics (absmax 0.03125).
// ---------------------------------------------------------------------------
__global__ __launch_bounds__(512, 2) void gemm_kernel(
    const __bf16* __restrict__ Wm, const float* __restrict__ E,
    float* __restrict__ out) {
  const int orig = blockIdx.x;  // 1024
  const int wg = (orig & 7) * 128 + (orig >> 3);  // bijective XCD swizzle
  const int mt = wg & 3;
  const int nt = (wg >> 2) & 15;
  const int b = wg >> 6;
  const int m0 = mt * BM, n0 = nt * BN;

  __shared__ __align__(16) char smem[147456];
  char* const A0_ = smem;            // 3 x 16 KB A slots
  char* const A1_ = smem + 16384;
  char* const A2_ = smem + 32768;
  char* const B0_ = smem + 49152;    // 3 x 32 KB B slots (fp32 [32k][256n])
  char* const B1_ = smem + 81920;
  char* const B2_ = smem + 114688;

  const int tid = threadIdx.x;  // 512
  const int lane = tid & 63;
  const int wid = tid >> 6;  // 0..7
  const int wr = wid >> 2;   // 0..1
  const int wc = wid & 3;    // 0..3
  const int ml = lane & 15;
  const int kg = lane >> 4;

  // ---- A staging: 256 rows x 32k bf16 = 16 KB = 2 rounds; 64-B rows of
  //      4 x 16B units, stored-unit pre-swizzle u' = u ^ (row&3) ----
  const int arow = tid >> 2;                 // 0..127 (+128 on round 1)
  const int au = (tid & 3) ^ (arow & 3);     // original unit fetched
  const __bf16* Ag = Wm + ((size_t)(b * MDIM + m0 + arow)) * KDIM + au * 8;

  // ---- B staging: [32k][256n] fp32 = 32 KB = 4 rounds of 8 k-rows.
  //      Rotation: LDS float-pos f in row k holds n = (f - 8*(k>>3)) & 255;
  //      thread fetches the rotated source quad (16B aligned, no straddle).
  const int bk = tid >> 6;  // k within round-group: 0..7
  const int bq = tid & 63;  // float-quad position in row
  const float* Eg = E + (size_t)b * KDIM * NDIM + n0;

  // ---- compute-side fragment addressing ----
  // A frag: row = wr*128 + (qm*4+i)*16 + ml ; read unit pos = kg^(ml&3)
  const int aoff = wr * 8192 + ml * 64 + ((kg ^ (ml & 3)) * 16);
  // B frag: nn = wc*64 + nf*16 + ml ; col = (nn + 8*kg) & 255 ; k = kg*8+j
  const int cbase = wc * 64 + ml + 8 * kg;

  f32x4 acc[8][4];
#pragma unroll
  for (int i = 0; i < 8; ++i)
#pragma unroll
    for (int j = 0; j < 4; ++j) acc[i][j] = (f32x4){0.f, 0.f, 0.f, 0.f};

  auto stage = [&](char* Ab, char* Bb, int kt) {
#pragma unroll
    for (int r = 0; r < 2; ++r)
      gload_lds16(Ag + (size_t)(128 * r) * KDIM + kt * BK,
                  Ab + tid * 16 + r * 8192);
#pragma unroll
    for (int r = 0; r < 4; ++r)
      gload_lds16(Eg + (size_t)(kt * BK + bk + 8 * r) * NDIM +
                      ((bq * 4 + 256 - 8 * r) & 255),
                  Bb + tid * 16 + r * 8192);
  };
  auto rdA = [&](bf16x8 (&d)[4], const char* Ab, int qm) {
#pragma unroll
    for (int i = 0; i < 4; ++i)
      d[i] = *reinterpret_cast<const bf16x8*>(Ab + aoff + qm * 4096 +
                                              i * 1024);
  };
  auto rdB = [&](bf16x8 (&d)[4], const char* Bb) {
#pragma unroll
    for (int nf = 0; nf < 4; ++nf) {
      const char* p = Bb + kg * 8192 + (((cbase + nf * 16) & 255) << 2);
      bf16x8 v;
#pragma unroll
      for (int j = 0; j < 8; ++j)
        v[j] = (__bf16)*reinterpret_cast<const float*>(p + j * 1024);
      d[nf] = v;
    }
  };
  auto mfma16 = [&](bf16x8 (&a)[4], bf16x8 (&bv)[4], int qm) {
    __builtin_amdgcn_s_setprio(1);
#pragma unroll
    for (int i = 0; i < 4; ++i)
#pragma unroll
      for (int nf = 0; nf < 4; ++nf)
        acc[qm * 4 + i][nf] = __builtin_amdgcn_mfma_f32_16x16x32_bf16(
            a[i], bv[nf], acc[qm * 4 + i][nf], 0, 0, 0);
    __builtin_amdgcn_s_setprio(0);
  };

  bf16x8 af0[4], af1[4], bf[4];

  // ---- prologue: stage tile0 -> slot0, tile1 -> slot1 (order pinned);
  //      vmcnt(6) drains tile0's 6; pre-read tile0 frags ----
  stage(A0_, B0_, 0);
  FENCE();  // keep tile0's 6 loads older than tile1's in the VMEM queue
  stage(A1_, B1_, 1);
  VMC6();
  BAR();
  rdB(bf, B0_);
  rdA(af0, A0_, 0);

  char *Ac = A0_, *An = A1_, *Ast = A2_;
  char *Bc = B0_, *Bn = B1_, *Bst = B2_;

#pragma unroll 1
  for (int t = 0; t < NT; ++t) {
    const bool pf1 = (t + 1 < NT);
    const bool pf2 = (t + 2 < NT);

    // R0: read A(q1); issue stage(t+2) into the freed slot; MFMA q0
    rdA(af1, Ac, 1);
    if (pf2) stage(Ast, Bst, t + 2);
    mfma16(af0, bf, 0);

    // R1: MFMA q1 (pure compute; other wave's loads/LDS overlap here)
    mfma16(af1, bf, 1);

    // sync: counted -- drains stage(t+1), leaves stage(t+2) in flight.
    // No lgkm drain needed: no ds_writes; frag reads completed via the
    // MFMAs' operand waits before this point.
    if (pf2) {
      VMC6();
    } else {
      VMC0();  // tail: drain the last staged tile
    }
    BAR();

    // pre-read tile t+1 frags (slots An/Bn, just published)
    if (pf1) {
      rdB(bf, Bn);
      rdA(af0, An, 0);
    }

    // rotate tri-buffers
    char* ta = Ac; Ac = An; An = Ast; Ast = ta;
    char* tb = Bc; Bc = Bn; Bn = Bst; Bst = tb;
  }

  // ---- epilogue (unchanged) ----
  float* ob = out + ((size_t)(b * MDIM + m0 + wr * 128 + kg * 4)) * NDIM +
              n0 + wc * 64 + ml;
#pragma unroll
  for (int mf = 0; mf < 8; ++mf)
#pragma unroll
    for (int nf = 0; nf < 4; ++nf) {
      const f32x4 a = acc[mf][nf];
      float* p = ob + (size_t)mf * 16 * NDIM + nf * 16;
#pragma unroll
      for (int q = 0; q < 4; ++q) p[(size_t)q * NDIM] = a[q];
    }
}

extern "C" void kernel_launch(void* const* d_in, const int* in_sizes, int n_in,
                              void* d_out, int out_size, void* d_ws,
                              size_t ws_size, hipStream_t stream) {
  (void)in_sizes;
  (void)n_in;
  (void)out_size;
  (void)ws_size;
  const float* Efou = (const float*)d_in[0];
  const float* y = (const float*)d_in[1];
  const float* weight = (const float*)d_in[2];
  float* outp = (float*)d_out;
  __bf16* wm = (__bf16*)d_ws;  // 32 MB

  modw_kernel<<<dim3(BATCH * MDIM), dim3(256), 0, stream>>>(weight, y, wm);
  gemm_kernel<<<dim3(BATCH * (MDIM / BM) * (NDIM / BN)), dim3(512), 0,
                stream>>>(wm, Efou, outp);
}

// Round 14
// 211.643 us; speedup vs baseline: 1.1061x; 1.1061x over previous
//
#include <hip/hip_runtime.h>
#include <hip/hip_bf16.h>
#include <cstdint>
#include <cstddef>

typedef __bf16 bf16x8 __attribute__((ext_vector_type(8)));
typedef __bf16 bf16x4 __attribute__((ext_vector_type(4)));
typedef float f32x4 __attribute__((ext_vector_type(4)));

#define BATCH 16
#define MDIM 1024
#define NDIM 4096
#define KDIM 1024
#define BM 256
#define BN 256
#define BK 64
#define NKT (KDIM / BK)  // 16

__device__ __forceinline__ void gload_lds16(const void* g, void* l) {
  __builtin_amdgcn_global_load_lds(
      (const __attribute__((address_space(1))) void*)g,
      (__attribute__((address_space(3))) void*)l, 16, 0, 0);
}

#define BAR() __builtin_amdgcn_s_barrier()
#define SB() __builtin_amdgcn_sched_barrier(0)
#define FENCE() asm volatile("" ::: "memory")
#define LGKM0()                                        \
  do {                                                 \
    asm volatile("s_waitcnt lgkmcnt(0)" ::: "memory"); \
    SB();                                              \
  } while (0)
#define VMC32()                                        \
  do {                                                 \
    asm volatile("s_waitcnt vmcnt(32)" ::: "memory");  \
    SB();                                              \
  } while (0)
#define VMC0()                                         \
  do {                                                 \
    asm volatile("s_waitcnt vmcnt(0)" ::: "memory");   \
    SB();                                              \
  } while (0)

// ---------------------------------------------------------------------------
// Kernel 1: W~[b][o][i] bf16 into workspace (~10us).
// ---------------------------------------------------------------------------
__global__ __launch_bounds__(256) void modw_kernel(
    const float* __restrict__ weight, const float* __restrict__ y,
    __bf16* __restrict__ wm) {
  const int blk = blockIdx.x;  // 16384
  const int b = blk & 15;
  const int o = blk >> 4;
  const int t = threadIdx.x;
  const float4 w4 = reinterpret_cast<const float4*>(weight + (size_t)o * KDIM)[t];
  const float4 y4 = reinterpret_cast<const float4*>(y + (size_t)b * KDIM)[t];
  const float p0 = w4.x * y4.x, p1 = w4.y * y4.y;
  const float p2 = w4.z * y4.z, p3 = w4.w * y4.w;
  float s = p0 * p0 + p1 * p1 + p2 * p2 + p3 * p3;
#pragma unroll
  for (int off = 32; off >= 1; off >>= 1) s += __shfl_xor(s, off, 64);
  __shared__ float ps[4];
  if ((t & 63) == 0) ps[t >> 6] = s;
  __syncthreads();
  const float tot = ps[0] + ps[1] + ps[2] + ps[3];
  const float scale = 0.03125f;  // 1/sqrt(1024)
  const float dn = scale * rsqrtf(scale * scale * tot + 1e-8f);
  bf16x4 v;
  v[0] = (__bf16)(p0 * dn);
  v[1] = (__bf16)(p1 * dn);
  v[2] = (__bf16)(p2 * dn);
  v[3] = (__bf16)(p3 * dn);
  *reinterpret_cast<bf16x4*>(wm + ((size_t)b * MDIM + o) * KDIM + t * 4) = v;
}

// ---------------------------------------------------------------------------
// Kernel 2 (R6, session best @ 211.5-212.8us, reproduced 3x -- FINAL):
// fused 256x256x64, 8 waves, ONE sync point per K-tile, one-region fragment
// read-ahead, rotating frag slots.  Regions per tile t (steady state):
//   R0: rd af1<-(q1,k0);  writeB(Bo,br[t+1]);        MFMA(af0,bf0 ->acc q0)
//   R1: rd bf1<-(k1), af0<-(q0,k1); stageA(Ao,t+1);
//       loadB(br,t+2);                               MFMA(af1,bf0 ->acc q1)
//   R2: rd af1<-(q1,k1);                             MFMA(af0,bf1 ->acc q0)
//       LGKM0 ; VMC32 (tail: VMC0) ; BAR
//   R3: rd af0<-Ao(q0,k0), bf0<-Bo(k0)  [tile t+1];  MFMA(af1,bf1 ->acc q1)
// VMEM queue invariant at the counted wait: [stageA(4) older, br(32) younger]
// -> vmcnt(32) drains exactly the A-stage.
// Session A/B evidence (all on-HW): sync density +9%; staging placement,
// counted boundary vmcnt, frag read-ahead depth, 2-tile A pipeline: null;
// occupancy/persistence/vectorized-B/A-direct/both-gload_lds: regress.
// ---------------------------------------------------------------------------
__global__ __launch_bounds__(512, 2) void gemm_kernel(
    const __bf16* __restrict__ Wm, const float* __restrict__ E,
    float* __restrict__ out) {
  const int orig = blockIdx.x;  // 1024
  const int wg = (orig & 7) * 128 + (orig >> 3);  // bijective XCD swizzle
  const int mt = wg & 3;
  const int nt = (wg >> 2) & 15;
  const int b = wg >> 6;
  const int m0 = mt * BM, n0 = nt * BN;

  __shared__ __align__(16) char smem[131072];
  char* const A0_ = smem;
  char* const A1_ = smem + 32768;
  char* const B0_ = smem + 65536;
  char* const B1_ = smem + 98304;

  const int tid = threadIdx.x;  // 512
  const int lane = tid & 63;
  const int wid = tid >> 6;  // 0..7
  const int wr = wid >> 2;   // 0..1
  const int wc = wid & 3;    // 0..3
  const int ml = lane & 15;
  const int kg = lane >> 4;

  // ---- A staging ----
  const int arow = tid >> 3;                      // 0..63, +64/round
  const int aswz = ((tid & 7) ^ (arow & 7)) * 8;  // pre-swizzled k-elem off
  const __bf16* Ag = Wm + ((size_t)(b * MDIM + m0 + arow)) * KDIM + aswz;
  const int aldsOff = tid * 16;

  // ---- B staging ----
  const int bn1 = tid & 63;
  const int bkg = tid >> 6;
  typedef const __attribute__((address_space(1))) float gfloat;
  gfloat* Eg = (gfloat*)(E + (size_t)b * KDIM * NDIM +
                         (size_t)(bkg * 8) * NDIM + n0 + bn1);
  int bwr[4];
#pragma unroll
  for (int c = 0; c < 4; ++c) {
    const int n = bn1 + 64 * c;
    bwr[c] = n * 128 + ((bkg * 16) ^ ((n & 7) << 4));
  }

  // ---- compute-side fragment addressing ----
  const int colA = (kg * 16) ^ ((ml & 7) << 4);
  const int arB = (wr * 128 + ml) * 128;
  const int brB = (wc * 64 + ml) * 128;

  f32x4 acc[8][4];
#pragma unroll
  for (int i = 0; i < 8; ++i)
#pragma unroll
    for (int j = 0; j < 4; ++j) acc[i][j] = (f32x4){0.f, 0.f, 0.f, 0.f};

  auto stageA = [&](char* Ab, int kt) {
#pragma unroll
    for (int r = 0; r < 4; ++r)
      gload_lds16(Ag + (size_t)(64 * r) * KDIM + kt * BK,
                  Ab + aldsOff + r * 8192);
  };
  auto loadB = [&](float (&brr)[4][8], int kt) {
#pragma unroll
    for (int c = 0; c < 4; ++c)
#pragma unroll
      for (int j = 0; j < 8; ++j)
        brr[c][j] = Eg[(size_t)(kt * BK + j) * NDIM + 64 * c];
  };
  auto writeB = [&](char* Bb, float (&brr)[4][8]) {
#pragma unroll
    for (int c = 0; c < 4; ++c) {
      bf16x8 v;
#pragma unroll
      for (int j = 0; j < 8; ++j) v[j] = (__bf16)brr[c][j];
      *reinterpret_cast<bf16x8*>(Bb + bwr[c]) = v;
    }
  };
  auto rdA = [&](bf16x8 (&d)[4], const char* Ab, int qm, int kk) {
#pragma unroll
    for (int i = 0; i < 4; ++i)
      d[i] = *reinterpret_cast<const bf16x8*>(Ab + arB + (qm * 4 + i) * 2048 +
                                              (colA ^ (kk * 64)));
  };
  auto rdB = [&](bf16x8 (&d)[4], const char* Bb, int kk) {
#pragma unroll
    for (int nf = 0; nf < 4; ++nf)
      d[nf] = *reinterpret_cast<const bf16x8*>(Bb + brB + nf * 2048 +
                                               (colA ^ (kk * 64)));
  };
  auto mfma16 = [&](bf16x8 (&a)[4], bf16x8 (&bv)[4], int qm) {
    __builtin_amdgcn_s_setprio(1);
#pragma unroll
    for (int i = 0; i < 4; ++i)
#pragma unroll
      for (int nf = 0; nf < 4; ++nf)
        acc[qm * 4 + i][nf] = __builtin_amdgcn_mfma_f32_16x16x32_bf16(
            a[i], bv[nf], acc[qm * 4 + i][nf], 0, 0, 0);
    __builtin_amdgcn_s_setprio(0);
  };

  float br[4][8];          // B reg-stage, persistent
  bf16x8 af0[4], af1[4];   // rotating frag slots (q0 / q1 roles)
  bf16x8 bf0[4], bf1[4];   // rotating frag slots (kk0 / kk1 roles)

  // ---- prologue: tile0 into A0/B0 (full drain once); br <- tile1;
  //      pre-read R0 frags of tile0 ----
  {
    float brT[4][8];
    stageA(A0_, 0);  // queue [A0(4)]
    FENCE();
    loadB(brT, 0);     // [A0(4), brT(32)]
    writeB(B0_, brT);  // implicit vmcnt(0): all drained
    loadB(br, 1);      // [br1(32)] == loop-entry invariant
    LGKM0();
    BAR();
    rdA(af0, A0_, 0, 0);  // read-ahead for t=0 R0
    rdB(bf0, B0_, 0);
  }

  char* Ac = A0_;
  char* Ao = A1_;
  char* Bc = B0_;
  char* Bo = B1_;

#pragma unroll 1
  for (int t = 0; t < NKT; ++t) {
    const bool pf1 = (t + 1 < NKT);
    const bool pf2 = (t + 2 < NKT);

    // R0: read-ahead (q1,k0); publish B(t+1); MFMA q0k0
    rdA(af1, Ac, 1, 0);
    if (pf1) writeB(Bo, br);  // implicit wait: br(t+1), issued ~1 tile ago
    mfma16(af0, bf0, 0);

    // R1: read-ahead (k1),(q0,k1); stage A(t+1); prefetch br(t+2); MFMA q1k0
    rdB(bf1, Bc, 1);
    rdA(af0, Ac, 0, 1);
    if (pf1) stageA(Ao, t + 1);
    FENCE();  // pin VMEM order: stage older than br loads
    if (pf2) loadB(br, t + 2);
    mfma16(af1, bf0, 1);

    // R2: read-ahead (q1,k1); MFMA q0k1; single sync point
    rdA(af1, Ac, 1, 1);
    mfma16(af0, bf1, 0);
    LGKM0();  // my frag reads + my B ds_writes done
    if (pf2) {
      VMC32();  // queue [stageA(t+1) 4 | br(t+2) 32] -> drains the A stage
    } else {
      VMC0();   // tail: no br in flight; drain remaining stage
    }
    BAR();

    // R3: read-ahead tile t+1 frags from Ao/Bo; MFMA q1k1
    if (pf1) {
      rdA(af0, Ao, 0, 0);
      rdB(bf0, Bo, 0);
    }
    mfma16(af1, bf1, 1);

    char* ta = Ac; Ac = Ao; Ao = ta;
    char* tb = Bc; Bc = Bo; Bo = tb;
  }

  // ---- epilogue ----
  float* ob = out + ((size_t)(b * MDIM + m0 + wr * 128 + kg * 4)) * NDIM +
              n0 + wc * 64 + ml;
#pragma unroll
  for (int mf = 0; mf < 8; ++mf)
#pragma unroll
    for (int nf = 0; nf < 4; ++nf) {
      const f32x4 a = acc[mf][nf];
      float* p = ob + (size_t)mf * 16 * NDIM + nf * 16;
#pragma unroll
      for (int q = 0; q < 4; ++q) p[(size_t)q * NDIM] = a[q];
    }
}

extern "C" void kernel_launch(void* const* d_in, const int* in_sizes, int n_in,
                              void* d_out, int out_size, void* d_ws,
                              size_t ws_size, hipStream_t stream) {
  (void)in_sizes;
  (void)n_in;
  (void)out_size;
  (void)ws_size;
  const float* Efou = (const float*)d_in[0];
  const float* y = (const float*)d_in[1];
  const float* weight = (const float*)d_in[2];
  float* outp = (float*)d_out;
  __bf16* wm = (__bf16*)d_ws;  // 32 MB

  modw_kernel<<<dim3(BATCH * MDIM), dim3(256), 0, stream>>>(weight, y, wm);
  gemm_kernel<<<dim3(BATCH * (MDIM / BM) * (NDIM / BN)), dim3(512), 0,
                stream>>>(wm, Efou, outp);
}